// Round 4
// baseline (1223.134 us; speedup 1.0000x reference)
//
#include <hip/hip_runtime.h>
#include <math.h>

#define DIMC 1024
#define NHEADC 16
#define DKC 64
#define HIDC 8192
#define TSEQ 2048
#define BATCH 2
#define NROWS (BATCH*TSEQ)   // 4096
#define EPSF 1e-5f

typedef __attribute__((ext_vector_type(8))) short short8;
typedef __attribute__((ext_vector_type(4))) float floatx4;

// ---------------- helpers ----------------
__device__ __forceinline__ ushort f2bf(float f){
  unsigned u = __float_as_uint(f);
  unsigned r = (u + 0x7FFFu + ((u>>16)&1u)) >> 16;
  return (ushort)r;
}
__device__ __forceinline__ floatx4 mfma16(short8 a, short8 b, floatx4 c){
  return __builtin_amdgcn_mfma_f32_16x16x32_bf16(a, b, c, 0, 0, 0);
}
__device__ __forceinline__ void gld_lds16(const void* g, void* l){
  __builtin_amdgcn_global_load_lds((const __attribute__((address_space(1))) unsigned*)g,
                                   (__attribute__((address_space(3))) unsigned*)l, 16, 0, 0);
}
__device__ __forceinline__ float wred_add(float v){
  #pragma unroll
  for (int o = 32; o > 0; o >>= 1) v += __shfl_xor(v, o, 64);
  return v;
}
__device__ __forceinline__ float wred_max(float v){
  #pragma unroll
  for (int o = 32; o > 0; o >>= 1) v = fmaxf(v, __shfl_xor(v, o, 64));
  return v;
}

// ---------------- weight transpose + fp32->bf16 convert: W[K][N] -> WT[N][K] ----
__global__ __launch_bounds__(256)
void wconv_t(const float* __restrict__ W, ushort* __restrict__ WT, int K, int N)
{
  __shared__ float tile[32][33];
  const int t = threadIdx.x, tx = t & 31, ty = t >> 5;
  const int n0 = blockIdx.x * 32, k0 = blockIdx.y * 32;
  #pragma unroll
  for (int r = 0; r < 4; ++r)
    tile[ty + r*8][tx] = W[(size_t)(k0 + ty + r*8) * N + n0 + tx];
  __syncthreads();
  #pragma unroll
  for (int r = 0; r < 4; ++r)
    WT[(size_t)(n0 + ty + r*8) * K + k0 + tx] = f2bf(tile[tx][ty + r*8]);
}

// ---------------- V transpose: qkv V-part -> vT[bh][64][2048] ----------------
__global__ __launch_bounds__(256)
void vtrans(const ushort* __restrict__ qkv, ushort* __restrict__ vT)
{
  const int d = threadIdx.x & 63, tp = threadIdx.x >> 6;
  const int bh = blockIdx.y; const int h = bh & 15, b = bh >> 4;
  const int t0 = blockIdx.x * 32 + tp * 8;
  const ushort* src = qkv + ((size_t)(b*TSEQ) + t0) * (3*DIMC) + 2*DIMC + h*DKC + d;
  ushort tmp[8];
  #pragma unroll
  for (int k = 0; k < 8; ++k) tmp[k] = src[(size_t)k * (3*DIMC)];
  *(short8*)&vT[((size_t)bh*DKC + d)*TSEQ + t0] = *(const short8*)tmp;
}

// ---------------- LayerNorm fp32 in -> bf16 out ----------------
__global__ __launch_bounds__(256)
void ln_bf16(const float* __restrict__ x, const float* __restrict__ g,
             const float* __restrict__ b, ushort* __restrict__ y)
{
  __shared__ float red[8];
  const int row = blockIdx.x;
  const float* xr = x + (size_t)row * DIMC;
  const int c = threadIdx.x * 4;
  float4 v = *(const float4*)&xr[c];
  float s  = v.x + v.y + v.z + v.w;
  float ss = v.x*v.x + v.y*v.y + v.z*v.z + v.w*v.w;
  s = wred_add(s); ss = wred_add(ss);
  const int warp = threadIdx.x >> 6, lane = threadIdx.x & 63;
  if (lane == 0) { red[warp] = s; red[4+warp] = ss; }
  __syncthreads();
  s  = red[0] + red[1] + red[2] + red[3];
  ss = red[4] + red[5] + red[6] + red[7];
  const float mu  = s  * (1.f/DIMC);
  const float var = ss * (1.f/DIMC) - mu*mu;
  const float rr  = rsqrtf(var + EPSF);
  const float4 gv = *(const float4*)&g[c];
  const float4 bv = *(const float4*)&b[c];
  ushort4 o;
  o.x = f2bf((v.x-mu)*rr*gv.x + bv.x);
  o.y = f2bf((v.y-mu)*rr*gv.y + bv.y);
  o.z = f2bf((v.z-mu)*rr*gv.z + bv.z);
  o.w = f2bf((v.w-mu)*rr*gv.w + bv.w);
  *(ushort4*)&y[(size_t)row*DIMC + c] = o;
}

// ---------------- bf16 MFMA GEMM: C[M,N] = A[M,K] @ BT[N,K]^T (+ epilogue) ----
#define M_PLAIN 0      // out bf16
#define M_RES 1        // out fp32: C = res + alpha*acc
#define M_BIAS_GELU 2  // out bf16: C = gelu_exact(acc + bias)
#define M_BIAS_RES 3   // out fp32: C = res + alpha*(acc + bias)

template<int MODE>
__global__ __launch_bounds__(256)
void gemm_bf16(const ushort* __restrict__ A, const ushort* __restrict__ BT,
               void* __restrict__ Cout, const int M, const int N, const int K,
               const float* __restrict__ bias, const float* __restrict__ res,
               const float* __restrict__ alphap)
{
  __shared__ __align__(16) ushort Al[4][128][8];
  __shared__ __align__(16) ushort Bl[4][128][8];
  const int t = threadIdx.x;
  const int lane = t & 63, warp = t >> 6;
  const int quad = lane >> 4, l16 = lane & 15;
  const int m0 = (warp & 1) * 64, n0 = (warp >> 1) * 64;
  const size_t row0 = (size_t)blockIdx.y * 128;
  const size_t col0 = (size_t)blockIdx.x * 128;

  const int c0 = t, c1 = t + 256;
  const int ar0 = c0 & 127, as0 = c0 >> 7;
  const int ar1 = c1 & 127, as1 = c1 >> 7;
  const ushort* pa0 = A  + (row0 + ar0) * (size_t)K + as0 * 8;
  const ushort* pa1 = A  + (row0 + ar1) * (size_t)K + as1 * 8;
  const ushort* pb0 = BT + (col0 + ar0) * (size_t)K + as0 * 8;
  const ushort* pb1 = BT + (col0 + ar1) * (size_t)K + as1 * 8;
  ushort* la0 = &Al[as0][ar0][0];
  ushort* la1 = &Al[as1][ar1][0];
  ushort* lb0 = &Bl[as0][ar0][0];
  ushort* lb1 = &Bl[as1][ar1][0];

  floatx4 acc[4][4];
  const floatx4 zf = {0.f, 0.f, 0.f, 0.f};
  #pragma unroll
  for (int i = 0; i < 4; ++i)
    #pragma unroll
    for (int j = 0; j < 4; ++j) acc[i][j] = zf;

  for (int k0 = 0; k0 < K; k0 += 32) {
    gld_lds16(pa0 + k0, la0);
    gld_lds16(pa1 + k0, la1);
    gld_lds16(pb0 + k0, lb0);
    gld_lds16(pb1 + k0, lb1);
    __syncthreads();
    short8 af[4], bfr[4];
    #pragma unroll
    for (int i = 0; i < 4; ++i) {
      af[i]  = *(const short8*)&Al[quad][m0 + i*16 + l16][0];
      bfr[i] = *(const short8*)&Bl[quad][n0 + i*16 + l16][0];
    }
    #pragma unroll
    for (int mt = 0; mt < 4; ++mt)
      #pragma unroll
      for (int nt = 0; nt < 4; ++nt)
        acc[mt][nt] = mfma16(af[mt], bfr[nt], acc[mt][nt]);
    __syncthreads();
  }

  float alpha = 0.f;
  if (MODE == M_RES || MODE == M_BIAS_RES) alpha = alphap[0];
  #pragma unroll
  for (int nt = 0; nt < 4; ++nt) {
    const size_t col = col0 + n0 + nt*16 + l16;
    float bv = 0.f;
    if (MODE == M_BIAS_GELU || MODE == M_BIAS_RES) bv = bias[col];
    #pragma unroll
    for (int mt = 0; mt < 4; ++mt) {
      const size_t r0 = row0 + m0 + mt*16 + quad*4;
      #pragma unroll
      for (int reg = 0; reg < 4; ++reg) {
        float v = acc[mt][nt][reg];
        if (MODE == M_BIAS_GELU || MODE == M_BIAS_RES) v += bv;
        if (MODE == M_BIAS_GELU) v = 0.5f*v*(1.f + erff(v*0.70710678118654752f));
        if (MODE == M_RES || MODE == M_BIAS_RES) v = res[(r0+reg)*(size_t)N + col] + alpha*v;
        if (MODE == M_PLAIN || MODE == M_BIAS_GELU)
          ((ushort*)Cout)[(r0+reg)*(size_t)N + col] = f2bf(v);
        else
          ((float*)Cout)[(r0+reg)*(size_t)N + col] = v;
      }
    }
  }
}

// ---------------- fused MFMA attention ----------------
// Block = 1024 thr (16 waves), 16 q rows of one (b,h). S strip 64 KB bf16.
// 2 blocks/CU x 16 waves = 32 waves/CU = 100% occupancy.
__device__ __forceinline__ int swzf(int q){ return ((q>>2) ^ q) & 7; }
__device__ __forceinline__ int sidx(int q, int j){
  return (q << 11) + ((((j >> 3) ^ swzf(q)) << 3) | (j & 7));
}

__global__ __launch_bounds__(1024, 8)
void attn_mfma(const ushort* __restrict__ qkv, const ushort* __restrict__ vT,
               const float* __restrict__ alpha_head, ushort* __restrict__ att)
{
  __shared__ __align__(16) ushort S[16*2048];
  __shared__ float Ored[3][4][16*17];
  const int t = threadIdx.x;
  const int lane = t & 63, warp = t >> 6;
  const int quad = lane >> 4, l16 = lane & 15;
  const int blk = blockIdx.x;            // 4096 = 32 bh * 128 q-chunks
  const int bh  = blk >> 7;
  const int q0  = (blk & 127) << 4;
  const int h = bh & (NHEADC-1), b = bh >> 4;
  const size_t rowbase = (size_t)b * TSEQ;
  const floatx4 zf = {0.f, 0.f, 0.f, 0.f};

  // --- Q A-frags: m=l16 (q_local), k=quad*8+[0,8) (+32). Raw scores (no 0.125;
  // scale folded into exp2 constant — order-preserving, exact on bf16).
  const ushort* Qp = qkv + (rowbase + q0 + l16) * (size_t)(3*DIMC) + h*DKC + quad*8;
  const short8 aq0 = *(const short8*)Qp;
  const short8 aq1 = *(const short8*)(Qp + 32);

  // --- phase 1: scores S[q][j] = Q.K^T, each wave covers 128 j ---
  const int j0w = warp * 128;
  #pragma unroll
  for (int jt = 0; jt < 8; ++jt) {
    const int j = j0w + jt*16;
    const ushort* Kp = qkv + (rowbase + j + l16) * (size_t)(3*DIMC) + DIMC + h*DKC + quad*8;
    const short8 kb0 = *(const short8*)Kp;
    const short8 kb1 = *(const short8*)(Kp + 32);
    floatx4 c = mfma16(aq0, kb0, zf);
    c = mfma16(aq1, kb1, c);
    #pragma unroll
    for (int r = 0; r < 4; ++r)
      S[sidx(quad*4 + r, j + l16)] = f2bf(c[r]);
  }
  __syncthreads();

  // --- phase 2: per-row exact top-64 + softmax mix; 1 row per wave ---
  const float SC2 = 0.125f * 1.4426950408889634f;   // (1/sqrt(dk)) * log2(e)
  const float gate = 1.f / (1.f + __expf(-alpha_head[h]));
  {
    const int q = warp;
    const int sbase = q << 11;
    const int swq = swzf(q);
    // lane owns pairs: j = 2*lane + 128*p, p in [0,16)
    unsigned key[32]; float ev[32];
    float mx = -3.0e38f;
    #pragma unroll
    for (int p = 0; p < 16; ++p) {
      const int j = 2*lane + 128*p;
      const int g = (j >> 3) ^ swq;
      const unsigned pr = *(const unsigned*)&S[sbase + (g << 3) + (j & 7)];
      const unsigned u0 = pr & 0xFFFFu, u1 = pr >> 16;
      key[2*p]   = (u0 & 0x8000u) ? ((~u0) & 0xFFFFu) : (u0 | 0x8000u);
      key[2*p+1] = (u1 & 0x8000u) ? ((~u1) & 0xFFFFu) : (u1 | 0x8000u);
      const float v0 = __uint_as_float(pr << 16);
      const float v1 = __uint_as_float(pr & 0xFFFF0000u);
      ev[2*p] = v0; ev[2*p+1] = v1;
      mx = fmaxf(mx, fmaxf(v0, v1));
    }
    mx = wred_max(mx);
    const float nc = -mx * SC2;
    float sum_all = 0.f;
    #pragma unroll
    for (int i = 0; i < 32; ++i) { ev[i] = exp2f(fmaf(ev[i], SC2, nc)); sum_all += ev[i]; }
    sum_all = wred_add(sum_all);

    // radix-select 64th largest: counts via ballot -> scalar pipe
    unsigned prefix = 0u;
    for (int bit = 15; bit >= 0; --bit) {
      const unsigned cand = prefix | (1u << bit);
      int c = 0;
      #pragma unroll
      for (int i = 0; i < 32; ++i)
        c += __popcll(__ballot(key[i] >= cand));
      if (c >= 64) prefix = cand;
    }
    // strict-greater pass
    unsigned inmask = 0u;
    float sum_sp = 0.f;
    int c_gt = 0;
    #pragma unroll
    for (int i = 0; i < 32; ++i) {
      const bool gbit = key[i] > prefix;
      c_gt += __popcll(__ballot(gbit));
      if (gbit) { inmask |= (1u << i); sum_sp += ev[i]; }
    }
    const int need_eq = 64 - c_gt;   // >=1; ties by lowest j (jax top_k)
    int eqb = 0;
    const unsigned long long below = (1ULL << lane) - 1ULL;
    for (int p = 0; p < 16; ++p) {
      const bool e0 = (key[2*p]   == prefix);
      const bool e1 = (key[2*p+1] == prefix);
      const unsigned long long m0 = __ballot(e0);
      const unsigned long long m1 = __ballot(e1);
      if (m0 | m1) {
        const int r0 = eqb + __popcll(m0 & below) + __popcll(m1 & below);
        const int r1 = r0 + (e0 ? 1 : 0);
        if (e0 && r0 < need_eq) { inmask |= (1u << (2*p));   sum_sp += ev[2*p]; }
        if (e1 && r1 < need_eq) { inmask |= (1u << (2*p+1)); sum_sp += ev[2*p+1]; }
        eqb += __popcll(m0) + __popcll(m1);
      }
    }
    sum_sp = wred_add(sum_sp);

    const float cd  = gate / sum_all;
    const float cdc = cd + (1.f - gate) / sum_sp;
    #pragma unroll
    for (int p = 0; p < 16; ++p) {
      const float w0 = ev[2*p]   * (((inmask >> (2*p))   & 1u) ? cdc : cd);
      const float w1 = ev[2*p+1] * (((inmask >> (2*p+1)) & 1u) ? cdc : cd);
      const int j = 2*lane + 128*p;
      const int g = (j >> 3) ^ swq;
      *(unsigned*)&S[sbase + (g << 3) + (j & 7)] =
          (unsigned)f2bf(w0) | ((unsigned)f2bf(w1) << 16);
    }
  }
  __syncthreads();

  // --- phase 3: O[16q x 64d] = W[16x2048] @ V[2048x64]; 4x4 (n,k) wave grid ---
  const int ng = warp & 3, kq = warp >> 2;
  const int n0  = ng * 16;
  const int kt0 = kq * 16;
  floatx4 o = zf, o2 = zf;
  const ushort* Vb = vT + ((size_t)bh*DKC + n0 + l16) * TSEQ + quad*8;
  #pragma unroll 2
  for (int tt = 0; tt < 16; tt += 2) {
    const int kt = kt0 + tt;
    const short8 a0 = *(const short8*)&S[sidx(l16, kt*32 + quad*8)];
    const short8 vb0 = *(const short8*)(Vb + (size_t)kt*32);
    const short8 a1 = *(const short8*)&S[sidx(l16, (kt+1)*32 + quad*8)];
    const short8 vb1 = *(const short8*)(Vb + (size_t)(kt+1)*32);
    o  = mfma16(a0, vb0, o);
    o2 = mfma16(a1, vb1, o2);
  }
  o = o + o2;
  if (kq > 0) {
    #pragma unroll
    for (int r = 0; r < 4; ++r) Ored[kq-1][ng][(quad*4+r)*17 + l16] = o[r];
  }
  __syncthreads();
  if (kq == 0) {
    #pragma unroll
    for (int r = 0; r < 4; ++r) {
      const int ri = (quad*4+r)*17 + l16;
      const float v = o[r] + Ored[0][ng][ri] + Ored[1][ng][ri] + Ored[2][ng][ri];
      att[(rowbase + q0 + quad*4 + r) * (size_t)DIMC + h*DKC + n0 + l16] = f2bf(v);
    }
  }
}

// ---------------- launch ----------------
extern "C" void kernel_launch(void* const* d_in, const int* in_sizes, int n_in,
                              void* d_out, int out_size, void* d_ws, size_t ws_size,
                              hipStream_t stream)
{
  const float* x          = (const float*)d_in[0];
  const float* ln1_g      = (const float*)d_in[1];
  const float* ln1_b      = (const float*)d_in[2];
  const float* w_qkv      = (const float*)d_in[3];
  const float* alpha_head = (const float*)d_in[4];
  const float* w_out      = (const float*)d_in[5];
  const float* ln2_g      = (const float*)d_in[6];
  const float* ln2_b      = (const float*)d_in[7];
  const float* w1         = (const float*)d_in[8];
  const float* b1         = (const float*)d_in[9];
  const float* w2         = (const float*)d_in[10];
  const float* b2         = (const float*)d_in[11];
  const float* alphap     = (const float*)d_in[12];
  float* out = (float*)d_out;

  char* ws = (char*)d_ws;
  ushort* wT_qkv = (ushort*)(ws);                         //  6 MB  [3072][1024]
  ushort* wT_out = (ushort*)(ws + 6291456);               //  2 MB  [1024][1024]
  ushort* wT_1   = (ushort*)(ws + 8388608);               // 16 MB  [8192][1024]
  ushort* wT_2   = (ushort*)(ws + 25165824);              // 16 MB  [1024][8192]
  ushort* xn     = (ushort*)(ws + 41943040);              //  8 MB  [4096][1024]
  ushort* qkv    = (ushort*)(ws + 50331648);              // 24 MB  [4096][3072]
  ushort* attb   = (ushort*)(ws + 75497472);              //  8 MB  [4096][1024]
  float*  x2     = (float*) (ws + 83886080);              // 16 MB  [4096][1024]
  ushort* hbuf   = (ushort*)(ws + 100663296);             // 64 MB  [4096][8192]
  ushort* vT     = (ushort*)(ws + 167772160);             //  8 MB  [32][64][2048]

  wconv_t<<<dim3(3072/32, 1024/32), 256, 0, stream>>>(w_qkv, wT_qkv, 1024, 3072);
  wconv_t<<<dim3(1024/32, 1024/32), 256, 0, stream>>>(w_out, wT_out, 1024, 1024);
  wconv_t<<<dim3(8192/32, 1024/32), 256, 0, stream>>>(w1,    wT_1,   1024, 8192);
  wconv_t<<<dim3(1024/32, 8192/32), 256, 0, stream>>>(w2,    wT_2,   8192, 1024);

  // 1) LN1 -> bf16
  ln_bf16<<<NROWS, 256, 0, stream>>>(x, ln1_g, ln1_b, xn);
  // 2) qkv = xn @ w_qkv  (bf16 out)
  gemm_bf16<M_PLAIN><<<dim3(3*DIMC/128, NROWS/128), 256, 0, stream>>>(
      xn, wT_qkv, qkv, NROWS, 3*DIMC, DIMC, nullptr, nullptr, nullptr);
  // 2b) V transpose
  vtrans<<<dim3(64, 32), 256, 0, stream>>>(qkv, vT);
  // 3) adaptive sparse attention (bf16 out)
  attn_mfma<<<4096, 1024, 0, stream>>>(qkv, vT, alpha_head, attb);
  // 4) x2 = x + alpha * (att @ w_out)  (fp32 out)
  gemm_bf16<M_RES><<<dim3(DIMC/128, NROWS/128), 256, 0, stream>>>(
      attb, wT_out, x2, NROWS, DIMC, DIMC, nullptr, x, alphap);
  // 5) LN2 -> bf16 (reuse xn)
  ln_bf16<<<NROWS, 256, 0, stream>>>(x2, ln2_g, ln2_b, xn);
  // 6) h = gelu(xn @ w1 + b1)  (bf16 out)
  gemm_bf16<M_BIAS_GELU><<<dim3(HIDC/128, NROWS/128), 256, 0, stream>>>(
      xn, wT_1, hbuf, NROWS, HIDC, DIMC, b1, nullptr, nullptr);
  // 7) out = x2 + alpha * (h @ w2 + b2)  (fp32 out)
  gemm_bf16<M_BIAS_RES><<<dim3(DIMC/128, NROWS/128), 256, 0, stream>>>(
      hbuf, wT_2, out, NROWS, DIMC, HIDC, b2, x2, alphap);
}

// Round 5
// 990.474 us; speedup vs baseline: 1.2349x; 1.2349x over previous
//
#include <hip/hip_runtime.h>
#include <hip/hip_bf16.h>
#include <math.h>

#define DIMC 1024
#define NHEADC 16
#define DKC 64
#define HIDC 8192
#define TSEQ 2048
#define BATCH 2
#define NROWS (BATCH*TSEQ)   // 4096
#define EPSF 1e-5f

typedef __attribute__((ext_vector_type(8))) short short8;
typedef __attribute__((ext_vector_type(4))) float floatx4;

// ---------------- helpers ----------------
__device__ __forceinline__ unsigned pk2bf(float a, float b){
  float2 t; t.x = a; t.y = b;
  __hip_bfloat162 h = __float22bfloat162_rn(t);   // v_cvt_pk_bf16_f32 on gfx950
  union { __hip_bfloat162 h; unsigned u; } cv; cv.h = h;
  return cv.u;                                    // a in low 16, b in high 16
}
__device__ __forceinline__ ushort f2bf(float f){
  return (ushort)(pk2bf(f, f) & 0xFFFFu);
}
__device__ __forceinline__ floatx4 mfma16(short8 a, short8 b, floatx4 c){
  return __builtin_amdgcn_mfma_f32_16x16x32_bf16(a, b, c, 0, 0, 0);
}
__device__ __forceinline__ void gld_lds16(const void* g, void* l){
  __builtin_amdgcn_global_load_lds((const __attribute__((address_space(1))) unsigned*)g,
                                   (__attribute__((address_space(3))) unsigned*)l, 16, 0, 0);
}
__device__ __forceinline__ float wred_add(float v){
  #pragma unroll
  for (int o = 32; o > 0; o >>= 1) v += __shfl_xor(v, o, 64);
  return v;
}
__device__ __forceinline__ float wred_max(float v){
  #pragma unroll
  for (int o = 32; o > 0; o >>= 1) v = fmaxf(v, __shfl_xor(v, o, 64));
  return v;
}

// ---------------- weight transpose + fp32->bf16 convert: W[K][N] -> WT[N][K] ----
__global__ __launch_bounds__(256)
void wconv_t(const float* __restrict__ W, ushort* __restrict__ WT, int K, int N)
{
  __shared__ float tile[32][33];
  const int t = threadIdx.x, tx = t & 31, ty = t >> 5;
  const int n0 = blockIdx.x * 32, k0 = blockIdx.y * 32;
  #pragma unroll
  for (int r = 0; r < 4; ++r)
    tile[ty + r*8][tx] = W[(size_t)(k0 + ty + r*8) * N + n0 + tx];
  __syncthreads();
  #pragma unroll
  for (int r = 0; r < 4; ++r)
    WT[(size_t)(n0 + ty + r*8) * K + k0 + tx] = f2bf(tile[tx][ty + r*8]);
}

// ---------------- V transpose: qkv V-part -> vT[bh][64][2048] ----------------
__global__ __launch_bounds__(256)
void vtrans(const ushort* __restrict__ qkv, ushort* __restrict__ vT)
{
  const int d = threadIdx.x & 63, tp = threadIdx.x >> 6;
  const int bh = blockIdx.y; const int h = bh & 15, b = bh >> 4;
  const int t0 = blockIdx.x * 32 + tp * 8;
  const ushort* src = qkv + ((size_t)(b*TSEQ) + t0) * (3*DIMC) + 2*DIMC + h*DKC + d;
  ushort tmp[8];
  #pragma unroll
  for (int k = 0; k < 8; ++k) tmp[k] = src[(size_t)k * (3*DIMC)];
  *(short8*)&vT[((size_t)bh*DKC + d)*TSEQ + t0] = *(const short8*)tmp;
}

// ---------------- LayerNorm fp32 in -> bf16 out ----------------
__global__ __launch_bounds__(256)
void ln_bf16(const float* __restrict__ x, const float* __restrict__ g,
             const float* __restrict__ b, ushort* __restrict__ y)
{
  __shared__ float red[8];
  const int row = blockIdx.x;
  const float* xr = x + (size_t)row * DIMC;
  const int c = threadIdx.x * 4;
  float4 v = *(const float4*)&xr[c];
  float s  = v.x + v.y + v.z + v.w;
  float ss = v.x*v.x + v.y*v.y + v.z*v.z + v.w*v.w;
  s = wred_add(s); ss = wred_add(ss);
  const int warp = threadIdx.x >> 6, lane = threadIdx.x & 63;
  if (lane == 0) { red[warp] = s; red[4+warp] = ss; }
  __syncthreads();
  s  = red[0] + red[1] + red[2] + red[3];
  ss = red[4] + red[5] + red[6] + red[7];
  const float mu  = s  * (1.f/DIMC);
  const float var = ss * (1.f/DIMC) - mu*mu;
  const float rr  = rsqrtf(var + EPSF);
  const float4 gv = *(const float4*)&g[c];
  const float4 bv = *(const float4*)&b[c];
  uint2 o;
  o.x = pk2bf((v.x-mu)*rr*gv.x + bv.x, (v.y-mu)*rr*gv.y + bv.y);
  o.y = pk2bf((v.z-mu)*rr*gv.z + bv.z, (v.w-mu)*rr*gv.w + bv.w);
  *(uint2*)&y[(size_t)row*DIMC + c] = o;
}

// ---------------- bf16 MFMA GEMM: C[M,N] = A[M,K] @ BT[N,K]^T (+ epilogue) ----
#define M_PLAIN 0      // out bf16
#define M_RES 1        // out fp32: C = res + alpha*acc
#define M_BIAS_GELU 2  // out bf16: C = gelu_exact(acc + bias)
#define M_BIAS_RES 3   // out fp32: C = res + alpha*(acc + bias)

template<int MODE>
__global__ __launch_bounds__(256)
void gemm_bf16(const ushort* __restrict__ A, const ushort* __restrict__ BT,
               void* __restrict__ Cout, const int M, const int N, const int K,
               const float* __restrict__ bias, const float* __restrict__ res,
               const float* __restrict__ alphap)
{
  __shared__ __align__(16) ushort Al[4][128][8];
  __shared__ __align__(16) ushort Bl[4][128][8];
  const int t = threadIdx.x;
  const int lane = t & 63, warp = t >> 6;
  const int quad = lane >> 4, l16 = lane & 15;
  const int m0 = (warp & 1) * 64, n0 = (warp >> 1) * 64;
  const size_t row0 = (size_t)blockIdx.y * 128;
  const size_t col0 = (size_t)blockIdx.x * 128;

  const int c0 = t, c1 = t + 256;
  const int ar0 = c0 & 127, as0 = c0 >> 7;
  const int ar1 = c1 & 127, as1 = c1 >> 7;
  const ushort* pa0 = A  + (row0 + ar0) * (size_t)K + as0 * 8;
  const ushort* pa1 = A  + (row0 + ar1) * (size_t)K + as1 * 8;
  const ushort* pb0 = BT + (col0 + ar0) * (size_t)K + as0 * 8;
  const ushort* pb1 = BT + (col0 + ar1) * (size_t)K + as1 * 8;
  ushort* la0 = &Al[as0][ar0][0];
  ushort* la1 = &Al[as1][ar1][0];
  ushort* lb0 = &Bl[as0][ar0][0];
  ushort* lb1 = &Bl[as1][ar1][0];

  floatx4 acc[4][4];
  const floatx4 zf = {0.f, 0.f, 0.f, 0.f};
  #pragma unroll
  for (int i = 0; i < 4; ++i)
    #pragma unroll
    for (int j = 0; j < 4; ++j) acc[i][j] = zf;

  for (int k0 = 0; k0 < K; k0 += 32) {
    gld_lds16(pa0 + k0, la0);
    gld_lds16(pa1 + k0, la1);
    gld_lds16(pb0 + k0, lb0);
    gld_lds16(pb1 + k0, lb1);
    __syncthreads();
    short8 af[4], bfr[4];
    #pragma unroll
    for (int i = 0; i < 4; ++i) {
      af[i]  = *(const short8*)&Al[quad][m0 + i*16 + l16][0];
      bfr[i] = *(const short8*)&Bl[quad][n0 + i*16 + l16][0];
    }
    #pragma unroll
    for (int mt = 0; mt < 4; ++mt)
      #pragma unroll
      for (int nt = 0; nt < 4; ++nt)
        acc[mt][nt] = mfma16(af[mt], bfr[nt], acc[mt][nt]);
    __syncthreads();
  }

  float alpha = 0.f;
  if (MODE == M_RES || MODE == M_BIAS_RES) alpha = alphap[0];
  #pragma unroll
  for (int nt = 0; nt < 4; ++nt) {
    const size_t col = col0 + n0 + nt*16 + l16;
    float bv = 0.f;
    if (MODE == M_BIAS_GELU || MODE == M_BIAS_RES) bv = bias[col];
    #pragma unroll
    for (int mt = 0; mt < 4; ++mt) {
      const size_t r0 = row0 + m0 + mt*16 + quad*4;
      #pragma unroll
      for (int reg = 0; reg < 4; ++reg) {
        float v = acc[mt][nt][reg];
        if (MODE == M_BIAS_GELU || MODE == M_BIAS_RES) v += bv;
        if (MODE == M_BIAS_GELU) v = 0.5f*v*(1.f + erff(v*0.70710678118654752f));
        if (MODE == M_RES || MODE == M_BIAS_RES) v = res[(r0+reg)*(size_t)N + col] + alpha*v;
        if (MODE == M_PLAIN || MODE == M_BIAS_GELU)
          ((ushort*)Cout)[(r0+reg)*(size_t)N + col] = f2bf(v);
        else
          ((float*)Cout)[(r0+reg)*(size_t)N + col] = v;
      }
    }
  }
}

// ---------------- fused MFMA attention ----------------
// Block = 1024 thr (16 waves), 16 q rows of one (b,h). S strip 64 KB bf16.
// Target: 2 blocks/CU x 16 waves = 100% occupancy => phase 2 must stay <=64 VGPR.
__device__ __forceinline__ int swzf(int q){ return ((q>>2) ^ q) & 7; }
__device__ __forceinline__ int sidx(int q, int j){
  return (q << 11) + ((((j >> 3) ^ swzf(q)) << 3) | (j & 7));
}

__global__ __launch_bounds__(1024, 8)
void attn_mfma(const ushort* __restrict__ qkv, const ushort* __restrict__ vT,
               const float* __restrict__ alpha_head, ushort* __restrict__ att)
{
  __shared__ __align__(16) ushort S[16*2048];
  __shared__ float Ored[3][4][16*17];
  const int t = threadIdx.x;
  const int lane = t & 63, warp = t >> 6;
  const int quad = lane >> 4, l16 = lane & 15;
  const int blk = blockIdx.x;            // 4096 = 32 bh * 128 q-chunks
  const int bh  = blk >> 7;
  const int q0  = (blk & 127) << 4;
  const int h = bh & (NHEADC-1), b = bh >> 4;
  const size_t rowbase = (size_t)b * TSEQ;
  const floatx4 zf = {0.f, 0.f, 0.f, 0.f};

  // --- phase 1: raw scores S[q][j] = Q.K^T (scale folded into exp2 constant) ---
  {
    const ushort* Qp = qkv + (rowbase + q0 + l16) * (size_t)(3*DIMC) + h*DKC + quad*8;
    const short8 aq0 = *(const short8*)Qp;
    const short8 aq1 = *(const short8*)(Qp + 32);
    const int j0w = warp * 128;
    #pragma unroll
    for (int jt = 0; jt < 8; ++jt) {
      const int j = j0w + jt*16;
      const ushort* Kp = qkv + (rowbase + j + l16) * (size_t)(3*DIMC) + DIMC + h*DKC + quad*8;
      const short8 kb0 = *(const short8*)Kp;
      const short8 kb1 = *(const short8*)(Kp + 32);
      floatx4 c = mfma16(aq0, kb0, zf);
      c = mfma16(aq1, kb1, c);
      #pragma unroll
      for (int r = 0; r < 4; ++r)
        S[sidx(quad*4 + r, j + l16)] = f2bf(c[r]);
    }
  }
  __syncthreads();

  // --- phase 2: per-row exact top-64 + softmax mix; 1 row per wave ---
  // Register budget: only sv[32] held; exp recomputed (spill >> recompute cost).
  const float SC2 = 0.125f * 1.4426950408889634f;   // (1/sqrt(dk)) * log2(e)
  const float gate = 1.f / (1.f + __expf(-alpha_head[h]));
  {
    const int q = warp;
    const int sbase = q << 11;
    const int swq = swzf(q);
    // lane owns pairs: j = 2*lane + 128*p, p in [0,16)
    float sv[32];
    float mx = -3.0e38f;
    #pragma unroll
    for (int p = 0; p < 16; ++p) {
      const int j = 2*lane + 128*p;
      const int g = (j >> 3) ^ swq;
      const unsigned pr = *(const unsigned*)&S[sbase + (g << 3) + (j & 7)];
      const float v0 = __uint_as_float(pr << 16);
      const float v1 = __uint_as_float(pr & 0xFFFF0000u);
      sv[2*p] = v0; sv[2*p+1] = v1;
      mx = fmaxf(mx, fmaxf(v0, v1));
    }
    mx = wred_max(mx);
    const float nc = -mx * SC2;

    // radix-select 64th largest in bf16-key space; compares in float domain.
    // key->float: k>=0x8000 ? (k-0x8000)<<16 : (0xFFFF-k)<<16  (monotone)
    unsigned prefix = 0u;
    for (int bit = 15; bit >= 0; --bit) {
      const unsigned cand = prefix | (1u << bit);
      const unsigned ub = (cand >= 0x8000u) ? (cand - 0x8000u) : (0xFFFFu - cand);
      const float candf = __uint_as_float(ub << 16);
      int c = 0;
      #pragma unroll
      for (int i = 0; i < 32; ++i)
        c += __popcll(__ballot(sv[i] >= candf));
      if (c >= 64) prefix = cand;
    }
    const unsigned ubf = (prefix >= 0x8000u) ? (prefix - 0x8000u) : (0xFFFFu - prefix);
    const float thf = __uint_as_float(ubf << 16);

    // classification: strict-greater, then ties by lowest j (jax top_k order)
    unsigned inmask = 0u;
    int c_gt = 0;
    #pragma unroll
    for (int i = 0; i < 32; ++i) {
      const bool gbit = sv[i] > thf;
      c_gt += __popcll(__ballot(gbit));
      if (gbit) inmask |= (1u << i);
    }
    const int need_eq = 64 - c_gt;   // >=1
    int eqb = 0;
    const unsigned long long below = (1ULL << lane) - 1ULL;
    for (int p = 0; p < 16; ++p) {
      const bool e0 = (sv[2*p]   == thf);
      const bool e1 = (sv[2*p+1] == thf);
      const unsigned long long m0 = __ballot(e0);
      const unsigned long long m1 = __ballot(e1);
      if (m0 | m1) {
        const int r0 = eqb + __popcll(m0 & below) + __popcll(m1 & below);
        const int r1 = r0 + (e0 ? 1 : 0);
        if (e0 && r0 < need_eq) inmask |= (1u << (2*p));
        if (e1 && r1 < need_eq) inmask |= (1u << (2*p+1));
        eqb += __popcll(m0) + __popcll(m1);
      }
    }

    // fused denominator pass (recompute exp)
    float sum_all = 0.f, sum_sp = 0.f;
    #pragma unroll
    for (int i = 0; i < 32; ++i) {
      const float e = exp2f(fmaf(sv[i], SC2, nc));
      sum_all += e;
      sum_sp  += ((inmask >> i) & 1u) ? e : 0.f;
    }
    sum_all = wred_add(sum_all);
    sum_sp  = wred_add(sum_sp);

    const float cd  = gate / sum_all;
    const float cdc = cd + (1.f - gate) / sum_sp;
    #pragma unroll
    for (int p = 0; p < 16; ++p) {
      const float e0 = exp2f(fmaf(sv[2*p],   SC2, nc));
      const float e1 = exp2f(fmaf(sv[2*p+1], SC2, nc));
      const float w0 = e0 * (((inmask >> (2*p))   & 1u) ? cdc : cd);
      const float w1 = e1 * (((inmask >> (2*p+1)) & 1u) ? cdc : cd);
      const int j = 2*lane + 128*p;
      const int g = (j >> 3) ^ swq;
      *(unsigned*)&S[sbase + (g << 3) + (j & 7)] = pk2bf(w0, w1);
    }
  }
  __syncthreads();

  // --- phase 3: O[16q x 64d] = W[16x2048] @ V[2048x64]; 4x4 (n,k) wave grid ---
  const int ng = warp & 3, kq = warp >> 2;
  const int n0  = ng * 16;
  const int kt0 = kq * 16;
  floatx4 o = zf, o2 = zf;
  const ushort* Vb = vT + ((size_t)bh*DKC + n0 + l16) * TSEQ + quad*8;
  #pragma unroll 2
  for (int tt = 0; tt < 16; tt += 2) {
    const int kt = kt0 + tt;
    const short8 a0 = *(const short8*)&S[sidx(l16, kt*32 + quad*8)];
    const short8 vb0 = *(const short8*)(Vb + (size_t)kt*32);
    const short8 a1 = *(const short8*)&S[sidx(l16, (kt+1)*32 + quad*8)];
    const short8 vb1 = *(const short8*)(Vb + (size_t)(kt+1)*32);
    o  = mfma16(a0, vb0, o);
    o2 = mfma16(a1, vb1, o2);
  }
  o = o + o2;
  if (kq > 0) {
    #pragma unroll
    for (int r = 0; r < 4; ++r) Ored[kq-1][ng][(quad*4+r)*17 + l16] = o[r];
  }
  __syncthreads();
  if (kq == 0) {
    #pragma unroll
    for (int r = 0; r < 4; ++r) {
      const int ri = (quad*4+r)*17 + l16;
      const float v = o[r] + Ored[0][ng][ri] + Ored[1][ng][ri] + Ored[2][ng][ri];
      att[(rowbase + q0 + quad*4 + r) * (size_t)DIMC + h*DKC + n0 + l16] = f2bf(v);
    }
  }
}

// ---------------- launch ----------------
extern "C" void kernel_launch(void* const* d_in, const int* in_sizes, int n_in,
                              void* d_out, int out_size, void* d_ws, size_t ws_size,
                              hipStream_t stream)
{
  const float* x          = (const float*)d_in[0];
  const float* ln1_g      = (const float*)d_in[1];
  const float* ln1_b      = (const float*)d_in[2];
  const float* w_qkv      = (const float*)d_in[3];
  const float* alpha_head = (const float*)d_in[4];
  const float* w_out      = (const float*)d_in[5];
  const float* ln2_g      = (const float*)d_in[6];
  const float* ln2_b      = (const float*)d_in[7];
  const float* w1         = (const float*)d_in[8];
  const float* b1         = (const float*)d_in[9];
  const float* w2         = (const float*)d_in[10];
  const float* b2         = (const float*)d_in[11];
  const float* alphap     = (const float*)d_in[12];
  float* out = (float*)d_out;

  char* ws = (char*)d_ws;
  ushort* wT_qkv = (ushort*)(ws);                         //  6 MB  [3072][1024]
  ushort* wT_out = (ushort*)(ws + 6291456);               //  2 MB  [1024][1024]
  ushort* wT_1   = (ushort*)(ws + 8388608);               // 16 MB  [8192][1024]
  ushort* wT_2   = (ushort*)(ws + 25165824);              // 16 MB  [1024][8192]
  ushort* xn     = (ushort*)(ws + 41943040);              //  8 MB  [4096][1024]
  ushort* qkv    = (ushort*)(ws + 50331648);              // 24 MB  [4096][3072]
  ushort* attb   = (ushort*)(ws + 75497472);              //  8 MB  [4096][1024]
  float*  x2     = (float*) (ws + 83886080);              // 16 MB  [4096][1024]
  ushort* hbuf   = (ushort*)(ws + 100663296);             // 64 MB  [4096][8192]
  ushort* vT     = (ushort*)(ws + 167772160);             //  8 MB  [32][64][2048]

  wconv_t<<<dim3(3072/32, 1024/32), 256, 0, stream>>>(w_qkv, wT_qkv, 1024, 3072);
  wconv_t<<<dim3(1024/32, 1024/32), 256, 0, stream>>>(w_out, wT_out, 1024, 1024);
  wconv_t<<<dim3(8192/32, 1024/32), 256, 0, stream>>>(w1,    wT_1,   1024, 8192);
  wconv_t<<<dim3(1024/32, 8192/32), 256, 0, stream>>>(w2,    wT_2,   8192, 1024);

  // 1) LN1 -> bf16
  ln_bf16<<<NROWS, 256, 0, stream>>>(x, ln1_g, ln1_b, xn);
  // 2) qkv = xn @ w_qkv  (bf16 out)
  gemm_bf16<M_PLAIN><<<dim3(3*DIMC/128, NROWS/128), 256, 0, stream>>>(
      xn, wT_qkv, qkv, NROWS, 3*DIMC, DIMC, nullptr, nullptr, nullptr);
  // 2b) V transpose
  vtrans<<<dim3(64, 32), 256, 0, stream>>>(qkv, vT);
  // 3) adaptive sparse attention (bf16 out)
  attn_mfma<<<4096, 1024, 0, stream>>>(qkv, vT, alpha_head, attb);
  // 4) x2 = x + alpha * (att @ w_out)  (fp32 out)
  gemm_bf16<M_RES><<<dim3(DIMC/128, NROWS/128), 256, 0, stream>>>(
      attb, wT_out, x2, NROWS, DIMC, DIMC, nullptr, x, alphap);
  // 5) LN2 -> bf16 (reuse xn)
  ln_bf16<<<NROWS, 256, 0, stream>>>(x2, ln2_g, ln2_b, xn);
  // 6) h = gelu(xn @ w1 + b1)  (bf16 out)
  gemm_bf16<M_BIAS_GELU><<<dim3(HIDC/128, NROWS/128), 256, 0, stream>>>(
      xn, wT_1, hbuf, NROWS, HIDC, DIMC, b1, nullptr, nullptr);
  // 7) out = x2 + alpha * (h @ w2 + b2)  (fp32 out)
  gemm_bf16<M_BIAS_RES><<<dim3(DIMC/128, NROWS/128), 256, 0, stream>>>(
      hbuf, wT_2, out, NROWS, DIMC, HIDC, b2, x2, alphap);
}

// Round 6
// 986.626 us; speedup vs baseline: 1.2397x; 1.0039x over previous
//
#include <hip/hip_runtime.h>
#include <hip/hip_bf16.h>
#include <math.h>

#define DIMC 1024
#define NHEADC 16
#define DKC 64
#define HIDC 8192
#define TSEQ 2048
#define BATCH 2
#define NROWS (BATCH*TSEQ)   // 4096
#define EPSF 1e-5f

typedef __attribute__((ext_vector_type(8))) short short8;
typedef __attribute__((ext_vector_type(4))) float floatx4;

// ---------------- helpers ----------------
__device__ __forceinline__ unsigned pk2bf(float a, float b){
  float2 t; t.x = a; t.y = b;
  __hip_bfloat162 h = __float22bfloat162_rn(t);   // v_cvt_pk_bf16_f32 on gfx950
  union { __hip_bfloat162 h; unsigned u; } cv; cv.h = h;
  return cv.u;                                    // a in low 16, b in high 16
}
__device__ __forceinline__ ushort f2bf(float f){
  return (ushort)(pk2bf(f, f) & 0xFFFFu);
}
__device__ __forceinline__ floatx4 mfma16(short8 a, short8 b, floatx4 c){
  return __builtin_amdgcn_mfma_f32_16x16x32_bf16(a, b, c, 0, 0, 0);
}
__device__ __forceinline__ void gld_lds16(const void* g, void* l){
  __builtin_amdgcn_global_load_lds((const __attribute__((address_space(1))) unsigned*)g,
                                   (__attribute__((address_space(3))) unsigned*)l, 16, 0, 0);
}
__device__ __forceinline__ float wred_add(float v){
  #pragma unroll
  for (int o = 32; o > 0; o >>= 1) v += __shfl_xor(v, o, 64);
  return v;
}
__device__ __forceinline__ float wred_max(float v){
  #pragma unroll
  for (int o = 32; o > 0; o >>= 1) v = fmaxf(v, __shfl_xor(v, o, 64));
  return v;
}
__device__ __forceinline__ float lo16f(unsigned u){ return __uint_as_float(u << 16); }
__device__ __forceinline__ float hi16f(unsigned u){ return __uint_as_float(u & 0xFFFF0000u); }

// ---------------- weight transpose + fp32->bf16 convert: W[K][N] -> WT[N][K] ----
__global__ __launch_bounds__(256)
void wconv_t(const float* __restrict__ W, ushort* __restrict__ WT, int K, int N)
{
  __shared__ float tile[32][33];
  const int t = threadIdx.x, tx = t & 31, ty = t >> 5;
  const int n0 = blockIdx.x * 32, k0 = blockIdx.y * 32;
  #pragma unroll
  for (int r = 0; r < 4; ++r)
    tile[ty + r*8][tx] = W[(size_t)(k0 + ty + r*8) * N + n0 + tx];
  __syncthreads();
  #pragma unroll
  for (int r = 0; r < 4; ++r)
    WT[(size_t)(n0 + ty + r*8) * K + k0 + tx] = f2bf(tile[tx][ty + r*8]);
}

// ---------------- V transpose: qkv V-part -> vT[bh][64][2048] ----------------
__global__ __launch_bounds__(256)
void vtrans(const ushort* __restrict__ qkv, ushort* __restrict__ vT)
{
  const int d = threadIdx.x & 63, tp = threadIdx.x >> 6;
  const int bh = blockIdx.y; const int h = bh & 15, b = bh >> 4;
  const int t0 = blockIdx.x * 32 + tp * 8;
  const ushort* src = qkv + ((size_t)(b*TSEQ) + t0) * (3*DIMC) + 2*DIMC + h*DKC + d;
  ushort tmp[8];
  #pragma unroll
  for (int k = 0; k < 8; ++k) tmp[k] = src[(size_t)k * (3*DIMC)];
  *(short8*)&vT[((size_t)bh*DKC + d)*TSEQ + t0] = *(const short8*)tmp;
}

// ---------------- LayerNorm fp32 in -> bf16 out ----------------
__global__ __launch_bounds__(256)
void ln_bf16(const float* __restrict__ x, const float* __restrict__ g,
             const float* __restrict__ b, ushort* __restrict__ y)
{
  __shared__ float red[8];
  const int row = blockIdx.x;
  const float* xr = x + (size_t)row * DIMC;
  const int c = threadIdx.x * 4;
  float4 v = *(const float4*)&xr[c];
  float s  = v.x + v.y + v.z + v.w;
  float ss = v.x*v.x + v.y*v.y + v.z*v.z + v.w*v.w;
  s = wred_add(s); ss = wred_add(ss);
  const int warp = threadIdx.x >> 6, lane = threadIdx.x & 63;
  if (lane == 0) { red[warp] = s; red[4+warp] = ss; }
  __syncthreads();
  s  = red[0] + red[1] + red[2] + red[3];
  ss = red[4] + red[5] + red[6] + red[7];
  const float mu  = s  * (1.f/DIMC);
  const float var = ss * (1.f/DIMC) - mu*mu;
  const float rr  = rsqrtf(var + EPSF);
  const float4 gv = *(const float4*)&g[c];
  const float4 bv = *(const float4*)&b[c];
  uint2 o;
  o.x = pk2bf((v.x-mu)*rr*gv.x + bv.x, (v.y-mu)*rr*gv.y + bv.y);
  o.y = pk2bf((v.z-mu)*rr*gv.z + bv.z, (v.w-mu)*rr*gv.w + bv.w);
  *(uint2*)&y[(size_t)row*DIMC + c] = o;
}

// ---------------- bf16 MFMA GEMM: C[M,N] = A[M,K] @ BT[N,K]^T (+ epilogue) ----
#define M_PLAIN 0      // out bf16
#define M_RES 1        // out fp32: C = res + alpha*acc
#define M_BIAS_GELU 2  // out bf16: C = gelu_exact(acc + bias)
#define M_BIAS_RES 3   // out fp32: C = res + alpha*(acc + bias)

template<int MODE>
__global__ __launch_bounds__(256)
void gemm_bf16(const ushort* __restrict__ A, const ushort* __restrict__ BT,
               void* __restrict__ Cout, const int M, const int N, const int K,
               const float* __restrict__ bias, const float* __restrict__ res,
               const float* __restrict__ alphap)
{
  __shared__ __align__(16) ushort Al[4][128][8];
  __shared__ __align__(16) ushort Bl[4][128][8];
  const int t = threadIdx.x;
  const int lane = t & 63, warp = t >> 6;
  const int quad = lane >> 4, l16 = lane & 15;
  const int m0 = (warp & 1) * 64, n0 = (warp >> 1) * 64;
  const size_t row0 = (size_t)blockIdx.y * 128;
  const size_t col0 = (size_t)blockIdx.x * 128;

  const int c0 = t, c1 = t + 256;
  const int ar0 = c0 & 127, as0 = c0 >> 7;
  const int ar1 = c1 & 127, as1 = c1 >> 7;
  const ushort* pa0 = A  + (row0 + ar0) * (size_t)K + as0 * 8;
  const ushort* pa1 = A  + (row0 + ar1) * (size_t)K + as1 * 8;
  const ushort* pb0 = BT + (col0 + ar0) * (size_t)K + as0 * 8;
  const ushort* pb1 = BT + (col0 + ar1) * (size_t)K + as1 * 8;
  ushort* la0 = &Al[as0][ar0][0];
  ushort* la1 = &Al[as1][ar1][0];
  ushort* lb0 = &Bl[as0][ar0][0];
  ushort* lb1 = &Bl[as1][ar1][0];

  floatx4 acc[4][4];
  const floatx4 zf = {0.f, 0.f, 0.f, 0.f};
  #pragma unroll
  for (int i = 0; i < 4; ++i)
    #pragma unroll
    for (int j = 0; j < 4; ++j) acc[i][j] = zf;

  for (int k0 = 0; k0 < K; k0 += 32) {
    gld_lds16(pa0 + k0, la0);
    gld_lds16(pa1 + k0, la1);
    gld_lds16(pb0 + k0, lb0);
    gld_lds16(pb1 + k0, lb1);
    __syncthreads();
    short8 af[4], bfr[4];
    #pragma unroll
    for (int i = 0; i < 4; ++i) {
      af[i]  = *(const short8*)&Al[quad][m0 + i*16 + l16][0];
      bfr[i] = *(const short8*)&Bl[quad][n0 + i*16 + l16][0];
    }
    #pragma unroll
    for (int mt = 0; mt < 4; ++mt)
      #pragma unroll
      for (int nt = 0; nt < 4; ++nt)
        acc[mt][nt] = mfma16(af[mt], bfr[nt], acc[mt][nt]);
    __syncthreads();
  }

  float alpha = 0.f;
  if (MODE == M_RES || MODE == M_BIAS_RES) alpha = alphap[0];
  #pragma unroll
  for (int nt = 0; nt < 4; ++nt) {
    const size_t col = col0 + n0 + nt*16 + l16;
    float bv = 0.f;
    if (MODE == M_BIAS_GELU || MODE == M_BIAS_RES) bv = bias[col];
    #pragma unroll
    for (int mt = 0; mt < 4; ++mt) {
      const size_t r0 = row0 + m0 + mt*16 + quad*4;
      #pragma unroll
      for (int reg = 0; reg < 4; ++reg) {
        float v = acc[mt][nt][reg];
        if (MODE == M_BIAS_GELU || MODE == M_BIAS_RES) v += bv;
        if (MODE == M_BIAS_GELU) v = 0.5f*v*(1.f + erff(v*0.70710678118654752f));
        if (MODE == M_RES || MODE == M_BIAS_RES) v = res[(r0+reg)*(size_t)N + col] + alpha*v;
        if (MODE == M_PLAIN || MODE == M_BIAS_GELU)
          ((ushort*)Cout)[(r0+reg)*(size_t)N + col] = f2bf(v);
        else
          ((float*)Cout)[(r0+reg)*(size_t)N + col] = v;
      }
    }
  }
}

// ---------------- fused MFMA attention ----------------
// Block = 1024 thr (16 waves), 16 q rows of one (b,h). S strip 64 KB bf16.
// Phase 2 keeps scores PACKED (pk[16] dwords = 32 bf16) and unpacks per use:
// persistent live set ~16 VGPR so the (1024,8) 64-reg budget holds w/o spill.
__device__ __forceinline__ int swzf(int q){ return ((q>>2) ^ q) & 7; }
__device__ __forceinline__ int sidx(int q, int j){
  return (q << 11) + ((((j >> 3) ^ swzf(q)) << 3) | (j & 7));
}

__global__ __launch_bounds__(1024, 8)
void attn_mfma(const ushort* __restrict__ qkv, const ushort* __restrict__ vT,
               const float* __restrict__ alpha_head, ushort* __restrict__ att)
{
  __shared__ __align__(16) ushort S[16*2048];
  __shared__ float Ored[3][4][16*17];
  const int t = threadIdx.x;
  const int lane = t & 63, warp = t >> 6;
  const int quad = lane >> 4, l16 = lane & 15;
  const int blk = blockIdx.x;            // 4096 = 32 bh * 128 q-chunks
  const int bh  = blk >> 7;
  const int q0  = (blk & 127) << 4;
  const int h = bh & (NHEADC-1), b = bh >> 4;
  const size_t rowbase = (size_t)b * TSEQ;
  const floatx4 zf = {0.f, 0.f, 0.f, 0.f};

  // --- phase 1: raw scores S[q][j] = Q.K^T (scale folded into exp2 constant) ---
  {
    const ushort* Qp = qkv + (rowbase + q0 + l16) * (size_t)(3*DIMC) + h*DKC + quad*8;
    const short8 aq0 = *(const short8*)Qp;
    const short8 aq1 = *(const short8*)(Qp + 32);
    const int j0w = warp * 128;
    #pragma unroll
    for (int jt = 0; jt < 8; ++jt) {
      const int j = j0w + jt*16;
      const ushort* Kp = qkv + (rowbase + j + l16) * (size_t)(3*DIMC) + DIMC + h*DKC + quad*8;
      const short8 kb0 = *(const short8*)Kp;
      const short8 kb1 = *(const short8*)(Kp + 32);
      floatx4 c = mfma16(aq0, kb0, zf);
      c = mfma16(aq1, kb1, c);
      #pragma unroll
      for (int r = 0; r < 4; ++r)
        S[sidx(quad*4 + r, j + l16)] = f2bf(c[r]);
    }
  }
  __syncthreads();

  // --- phase 2: per-row exact top-64 + softmax mix; 1 row per wave ---
  const float SC2 = 0.125f * 1.4426950408889634f;   // (1/sqrt(dk)) * log2(e)
  const float gate = 1.f / (1.f + __expf(-alpha_head[h]));
  {
    const int q = warp;
    const int sbase = q << 11;
    const int swq = swzf(q);
    // lane owns pairs: j = 2*lane + 128*p, p in [0,16); kept packed in pk[p]
    unsigned pk[16];
    float mx = -3.0e38f;
    #pragma unroll
    for (int p = 0; p < 16; ++p) {
      const int j = 2*lane + 128*p;
      const int g = (j >> 3) ^ swq;
      pk[p] = *(const unsigned*)&S[sbase + (g << 3) + (j & 7)];
      mx = fmaxf(mx, fmaxf(lo16f(pk[p]), hi16f(pk[p])));
    }
    mx = wred_max(mx);
    const float nc = -mx * SC2;

    // radix-select 64th largest in bf16-key space; compares in float domain.
    // key->float: k>=0x8000 ? (k-0x8000)<<16 : (0xFFFF-k)<<16  (monotone)
    unsigned prefix = 0u;
    for (int bit = 15; bit >= 0; --bit) {
      const unsigned cand = prefix | (1u << bit);
      const unsigned ub = (cand >= 0x8000u) ? (cand - 0x8000u) : (0xFFFFu - cand);
      const float candf = __uint_as_float(ub << 16);
      int c = 0;
      #pragma unroll
      for (int p = 0; p < 16; ++p) {
        c += __popcll(__ballot(lo16f(pk[p]) >= candf));
        c += __popcll(__ballot(hi16f(pk[p]) >= candf));
      }
      if (c >= 64) prefix = cand;
    }
    const unsigned ubf = (prefix >= 0x8000u) ? (prefix - 0x8000u) : (0xFFFFu - prefix);
    const float thf = __uint_as_float(ubf << 16);

    // classification: strict-greater, then ties by lowest j (jax top_k order)
    unsigned inmask = 0u;
    int c_gt = 0;
    #pragma unroll
    for (int p = 0; p < 16; ++p) {
      const bool g0 = lo16f(pk[p]) > thf;
      const bool g1 = hi16f(pk[p]) > thf;
      c_gt += __popcll(__ballot(g0));
      c_gt += __popcll(__ballot(g1));
      if (g0) inmask |= (1u << (2*p));
      if (g1) inmask |= (1u << (2*p+1));
    }
    const int need_eq = 64 - c_gt;   // >=1
    int eqb = 0;
    const unsigned long long below = (1ULL << lane) - 1ULL;
    for (int p = 0; p < 16; ++p) {
      const bool e0 = (lo16f(pk[p]) == thf);
      const bool e1 = (hi16f(pk[p]) == thf);
      const unsigned long long m0 = __ballot(e0);
      const unsigned long long m1 = __ballot(e1);
      if (m0 | m1) {
        const int r0 = eqb + __popcll(m0 & below) + __popcll(m1 & below);
        const int r1 = r0 + (e0 ? 1 : 0);
        if (e0 && r0 < need_eq) inmask |= (1u << (2*p));
        if (e1 && r1 < need_eq) inmask |= (1u << (2*p+1));
        eqb += __popcll(m0) + __popcll(m1);
      }
    }

    // denominators (exp recomputed from packed scores)
    float sum_all = 0.f, sum_sp = 0.f;
    #pragma unroll
    for (int p = 0; p < 16; ++p) {
      const float e0 = exp2f(fmaf(lo16f(pk[p]), SC2, nc));
      const float e1 = exp2f(fmaf(hi16f(pk[p]), SC2, nc));
      sum_all += e0 + e1;
      sum_sp  += ((inmask >> (2*p))   & 1u) ? e0 : 0.f;
      sum_sp  += ((inmask >> (2*p+1)) & 1u) ? e1 : 0.f;
    }
    sum_all = wred_add(sum_all);
    sum_sp  = wred_add(sum_sp);

    const float cd  = gate / sum_all;
    const float cdc = cd + (1.f - gate) / sum_sp;
    #pragma unroll
    for (int p = 0; p < 16; ++p) {
      const float e0 = exp2f(fmaf(lo16f(pk[p]), SC2, nc));
      const float e1 = exp2f(fmaf(hi16f(pk[p]), SC2, nc));
      const float w0 = e0 * (((inmask >> (2*p))   & 1u) ? cdc : cd);
      const float w1 = e1 * (((inmask >> (2*p+1)) & 1u) ? cdc : cd);
      const int j = 2*lane + 128*p;
      const int g = (j >> 3) ^ swq;
      *(unsigned*)&S[sbase + (g << 3) + (j & 7)] = pk2bf(w0, w1);
    }
  }
  __syncthreads();

  // --- phase 3: O[16q x 64d] = W[16x2048] @ V[2048x64]; 4x4 (n,k) wave grid ---
  const int ng = warp & 3, kq = warp >> 2;
  const int n0  = ng * 16;
  const int kt0 = kq * 16;
  floatx4 o = zf, o2 = zf;
  const ushort* Vb = vT + ((size_t)bh*DKC + n0 + l16) * TSEQ + quad*8;
  #pragma unroll 2
  for (int tt = 0; tt < 16; tt += 2) {
    const int kt = kt0 + tt;
    const short8 a0 = *(const short8*)&S[sidx(l16, kt*32 + quad*8)];
    const short8 vb0 = *(const short8*)(Vb + (size_t)kt*32);
    const short8 a1 = *(const short8*)&S[sidx(l16, (kt+1)*32 + quad*8)];
    const short8 vb1 = *(const short8*)(Vb + (size_t)(kt+1)*32);
    o  = mfma16(a0, vb0, o);
    o2 = mfma16(a1, vb1, o2);
  }
  o = o + o2;
  if (kq > 0) {
    #pragma unroll
    for (int r = 0; r < 4; ++r) Ored[kq-1][ng][(quad*4+r)*17 + l16] = o[r];
  }
  __syncthreads();
  if (kq == 0) {
    #pragma unroll
    for (int r = 0; r < 4; ++r) {
      const int ri = (quad*4+r)*17 + l16;
      const float v = o[r] + Ored[0][ng][ri] + Ored[1][ng][ri] + Ored[2][ng][ri];
      att[(rowbase + q0 + quad*4 + r) * (size_t)DIMC + h*DKC + n0 + l16] = f2bf(v);
    }
  }
}

// ---------------- launch ----------------
extern "C" void kernel_launch(void* const* d_in, const int* in_sizes, int n_in,
                              void* d_out, int out_size, void* d_ws, size_t ws_size,
                              hipStream_t stream)
{
  const float* x          = (const float*)d_in[0];
  const float* ln1_g      = (const float*)d_in[1];
  const float* ln1_b      = (const float*)d_in[2];
  const float* w_qkv      = (const float*)d_in[3];
  const float* alpha_head = (const float*)d_in[4];
  const float* w_out      = (const float*)d_in[5];
  const float* ln2_g      = (const float*)d_in[6];
  const float* ln2_b      = (const float*)d_in[7];
  const float* w1         = (const float*)d_in[8];
  const float* b1         = (const float*)d_in[9];
  const float* w2         = (const float*)d_in[10];
  const float* b2         = (const float*)d_in[11];
  const float* alphap     = (const float*)d_in[12];
  float* out = (float*)d_out;

  char* ws = (char*)d_ws;
  ushort* wT_qkv = (ushort*)(ws);                         //  6 MB  [3072][1024]
  ushort* wT_out = (ushort*)(ws + 6291456);               //  2 MB  [1024][1024]
  ushort* wT_1   = (ushort*)(ws + 8388608);               // 16 MB  [8192][1024]
  ushort* wT_2   = (ushort*)(ws + 25165824);              // 16 MB  [1024][8192]
  ushort* xn     = (ushort*)(ws + 41943040);              //  8 MB  [4096][1024]
  ushort* qkv    = (ushort*)(ws + 50331648);              // 24 MB  [4096][3072]
  ushort* attb   = (ushort*)(ws + 75497472);              //  8 MB  [4096][1024]
  float*  x2     = (float*) (ws + 83886080);              // 16 MB  [4096][1024]
  ushort* hbuf   = (ushort*)(ws + 100663296);             // 64 MB  [4096][8192]
  ushort* vT     = (ushort*)(ws + 167772160);             //  8 MB  [32][64][2048]

  wconv_t<<<dim3(3072/32, 1024/32), 256, 0, stream>>>(w_qkv, wT_qkv, 1024, 3072);
  wconv_t<<<dim3(1024/32, 1024/32), 256, 0, stream>>>(w_out, wT_out, 1024, 1024);
  wconv_t<<<dim3(8192/32, 1024/32), 256, 0, stream>>>(w1,    wT_1,   1024, 8192);
  wconv_t<<<dim3(1024/32, 8192/32), 256, 0, stream>>>(w2,    wT_2,   8192, 1024);

  // 1) LN1 -> bf16
  ln_bf16<<<NROWS, 256, 0, stream>>>(x, ln1_g, ln1_b, xn);
  // 2) qkv = xn @ w_qkv  (bf16 out)
  gemm_bf16<M_PLAIN><<<dim3(3*DIMC/128, NROWS/128), 256, 0, stream>>>(
      xn, wT_qkv, qkv, NROWS, 3*DIMC, DIMC, nullptr, nullptr, nullptr);
  // 2b) V transpose
  vtrans<<<dim3(64, 32), 256, 0, stream>>>(qkv, vT);
  // 3) adaptive sparse attention (bf16 out)
  attn_mfma<<<4096, 1024, 0, stream>>>(qkv, vT, alpha_head, attb);
  // 4) x2 = x + alpha * (att @ w_out)  (fp32 out)
  gemm_bf16<M_RES><<<dim3(DIMC/128, NROWS/128), 256, 0, stream>>>(
      attb, wT_out, x2, NROWS, DIMC, DIMC, nullptr, x, alphap);
  // 5) LN2 -> bf16 (reuse xn)
  ln_bf16<<<NROWS, 256, 0, stream>>>(x2, ln2_g, ln2_b, xn);
  // 6) h = gelu(xn @ w1 + b1)  (bf16 out)
  gemm_bf16<M_BIAS_GELU><<<dim3(HIDC/128, NROWS/128), 256, 0, stream>>>(
      xn, wT_1, hbuf, NROWS, HIDC, DIMC, b1, nullptr, nullptr);
  // 7) out = x2 + alpha * (h @ w2 + b2)  (fp32 out)
  gemm_bf16<M_BIAS_RES><<<dim3(DIMC/128, NROWS/128), 256, 0, stream>>>(
      hbuf, wT_2, out, NROWS, DIMC, HIDC, b2, x2, alphap);
}